// Round 1
// baseline (1032.277 us; speedup 1.0000x reference)
//
#include <hip/hip_runtime.h>

#define NN 4096
#define TSTEPS 8
#define EPSW 1e-12f

// ---------------------------------------------------------------------------
// Build: degree (column sums) + per-row edge counts
// ---------------------------------------------------------------------------
__global__ __launch_bounds__(256) void deg_counts_kernel(
    const int* __restrict__ rows, const int* __restrict__ cols,
    const float* __restrict__ ew, float* __restrict__ deg,
    int* __restrict__ counts, int E) {
  int e = blockIdx.x * 256 + threadIdx.x;
  if (e >= E) return;
  atomicAdd(deg + cols[e], ew[e]);
  atomicAdd(counts + rows[e], 1);
}

// Exclusive scan of 4096 counts -> row_ptr (single block, 1024 threads x 4)
__global__ __launch_bounds__(1024) void scan_kernel(const int* __restrict__ counts,
                                                    int* __restrict__ row_ptr) {
  __shared__ int sm[1024];
  int tid = threadIdx.x;
  int b = tid * 4;
  int c0 = counts[b], c1 = counts[b + 1], c2 = counts[b + 2], c3 = counts[b + 3];
  sm[tid] = c0 + c1 + c2 + c3;
  __syncthreads();
  for (int off = 1; off < 1024; off <<= 1) {
    int v = (tid >= off) ? sm[tid - off] : 0;
    __syncthreads();
    sm[tid] += v;
    __syncthreads();
  }
  int excl = (tid == 0) ? 0 : sm[tid - 1];
  row_ptr[b]     = excl;
  row_ptr[b + 1] = excl + c0;
  row_ptr[b + 2] = excl + c0 + c1;
  row_ptr[b + 3] = excl + c0 + c1 + c2;
  if (tid == 1023) row_ptr[NN] = sm[1023];
}

// Scatter edges into CSR order (col_s, w_s), w = ew / max(deg[col], eps)
__global__ __launch_bounds__(256) void csr_scatter_kernel(
    const int* __restrict__ rows, const int* __restrict__ cols,
    const float* __restrict__ ew, const float* __restrict__ deg,
    const int* __restrict__ row_ptr, int* __restrict__ fill,
    int* __restrict__ col_s, float* __restrict__ w_s, int E) {
  int e = blockIdx.x * 256 + threadIdx.x;
  if (e >= E) return;
  int r = rows[e], c = cols[e];
  float w = ew[e] / fmaxf(deg[c], EPSW);
  int pos = row_ptr[r] + atomicAdd(fill + r, 1);
  col_s[pos] = c;
  w_s[pos] = w;
}

// ---------------------------------------------------------------------------
// P1 = M restricted to column slab [c0, c0+S): scatter w at (row, col)
// ---------------------------------------------------------------------------
__global__ __launch_bounds__(256) void scatter_p1_kernel(
    const int* __restrict__ rows, const int* __restrict__ cols,
    const float* __restrict__ ew, const float* __restrict__ deg,
    float* __restrict__ buf, int E, int c0, int S) {
  int e = blockIdx.x * 256 + threadIdx.x;
  if (e >= E) return;
  int c = cols[e];
  int lc = c - c0;
  if (lc < 0 || lc >= S) return;
  int r = rows[e];
  float w = ew[e] / fmaxf(deg[c], EPSW);
  atomicAdd(buf + r * S + lc, w);
}

__global__ __launch_bounds__(256) void diag1_kernel(const float* __restrict__ buf,
                                                    float* __restrict__ diags,
                                                    int c0, int S) {
  int lc = blockIdx.x * 256 + threadIdx.x;
  if (lc >= S) return;
  int i = c0 + lc;
  diags[i] = buf[i * S + lc];  // diag row 0 (t=1)
}

// ---------------------------------------------------------------------------
// SpMM step: dst[i, :] = sum_{e in row i} w_e * src[col_e, :]  (slab of S cols)
// One block per row; S/4 threads, each owns one float4 of columns.
// Fused diag write: global column == row index i.
// ---------------------------------------------------------------------------
template <int S>
__global__ __launch_bounds__(S / 4) void spmm_kernel(
    const float* __restrict__ src, float* __restrict__ dst,
    const int* __restrict__ row_ptr, const int* __restrict__ col_s,
    const float* __restrict__ w_s, float* __restrict__ diags,
    int c0, int tIdx) {
  constexpr int CH = 64;
  int i = blockIdx.x;
  int tid = threadIdx.x;
  int e0 = row_ptr[i], e1 = row_ptr[i + 1];

  __shared__ int sc[CH];
  __shared__ float sw[CH];

  float4 acc = make_float4(0.f, 0.f, 0.f, 0.f);
  int coff = tid << 2;

  for (int base = e0; base < e1; base += CH) {
    int cnt = min(CH, e1 - base);
    if (tid < cnt) {
      sc[tid] = col_s[base + tid];
      sw[tid] = w_s[base + tid];
    }
    __syncthreads();
    int k = 0;
    for (; k + 4 <= cnt; k += 4) {
      int ca = sc[k], cb = sc[k + 1], cc = sc[k + 2], cd = sc[k + 3];
      float wa = sw[k], wb = sw[k + 1], wc = sw[k + 2], wd = sw[k + 3];
      float4 pa = *(const float4*)(src + ca * S + coff);
      float4 pb = *(const float4*)(src + cb * S + coff);
      float4 pc = *(const float4*)(src + cc * S + coff);
      float4 pd = *(const float4*)(src + cd * S + coff);
      acc.x += wa * pa.x + wb * pb.x + wc * pc.x + wd * pd.x;
      acc.y += wa * pa.y + wb * pb.y + wc * pc.y + wd * pd.y;
      acc.z += wa * pa.z + wb * pb.z + wc * pc.z + wd * pd.z;
      acc.w += wa * pa.w + wb * pb.w + wc * pc.w + wd * pd.w;
    }
    for (; k < cnt; ++k) {
      int cc2 = sc[k];
      float wv = sw[k];
      float4 p = *(const float4*)(src + cc2 * S + coff);
      acc.x += wv * p.x;
      acc.y += wv * p.y;
      acc.z += wv * p.z;
      acc.w += wv * p.w;
    }
    __syncthreads();
  }

  *(float4*)(dst + i * S + coff) = acc;

  // fused diagonal extraction: global col == i
  int lc = i - c0;
  if (lc >= 0 && lc < S && (lc >> 2) == tid) {
    int m = lc & 3;
    float v = (m == 0) ? acc.x : (m == 1) ? acc.y : (m == 2) ? acc.z : acc.w;
    diags[tIdx * NN + i] = v;
  }
}

// ---------------------------------------------------------------------------
// Finalize: X = [ones, diag_1..diag_8], standardize each column (ddof=0)
// out[i*9 + k]
// ---------------------------------------------------------------------------
__global__ __launch_bounds__(256) void finalize_kernel(const float* __restrict__ diags,
                                                       float* __restrict__ out) {
  int k = blockIdx.x;  // 0..8
  int tid = threadIdx.x;
  float vals[16];
  float sum = 0.f, sq = 0.f;
#pragma unroll
  for (int j = 0; j < 16; ++j) {
    int i = j * 256 + tid;
    float v = (k == 0) ? 1.0f : diags[(k - 1) * NN + i];
    vals[j] = v;
    sum += v;
    sq += v * v;
  }
#pragma unroll
  for (int off = 32; off; off >>= 1) {
    sum += __shfl_down(sum, off);
    sq += __shfl_down(sq, off);
  }
  __shared__ float s0[4], s1[4];
  __shared__ float smean, sinv;
  int wid = tid >> 6, lane = tid & 63;
  if (lane == 0) { s0[wid] = sum; s1[wid] = sq; }
  __syncthreads();
  if (tid == 0) {
    float S = s0[0] + s0[1] + s0[2] + s0[3];
    float Q = s1[0] + s1[1] + s1[2] + s1[3];
    float mean = S / (float)NN;
    float var = Q / (float)NN - mean * mean;
    var = fmaxf(var, 0.f);
    float sd = fmaxf(sqrtf(var), 1e-6f);
    smean = mean;
    sinv = 1.f / sd;
  }
  __syncthreads();
#pragma unroll
  for (int j = 0; j < 16; ++j) {
    int i = j * 256 + tid;
    out[i * (TSTEPS + 1) + k] = (vals[j] - smean) * sinv;
  }
}

// ---------------------------------------------------------------------------
// Host driver
// ---------------------------------------------------------------------------
template <int S>
static void run_slabs(const int* rows, const int* cols, const float* ew,
                      const float* deg, const int* row_ptr, const int* col_s,
                      const float* w_s, float* diags, float* bufA, float* bufB,
                      int E, hipStream_t stream) {
  int eb = (E + 255) / 256;
  for (int s = 0; s < NN / S; ++s) {
    int c0 = s * S;
    hipMemsetAsync(bufA, 0, (size_t)NN * S * sizeof(float), stream);
    scatter_p1_kernel<<<eb, 256, 0, stream>>>(rows, cols, ew, deg, bufA, E, c0, S);
    diag1_kernel<<<(S + 255) / 256, 256, 0, stream>>>(bufA, diags, c0, S);
    float* src = bufA;
    float* dst = bufB;
    for (int t = 2; t <= TSTEPS; ++t) {
      spmm_kernel<S><<<NN, S / 4, 0, stream>>>(src, dst, row_ptr, col_s, w_s,
                                               diags, c0, t - 1);
      float* tmp = src; src = dst; dst = tmp;
    }
  }
}

extern "C" void kernel_launch(void* const* d_in, const int* in_sizes, int n_in,
                              void* d_out, int out_size, void* d_ws, size_t ws_size,
                              hipStream_t stream) {
  const int* ei = (const int*)d_in[0];
  const float* ew = (const float*)d_in[1];
  int E = in_sizes[1];
  const int* rows = ei;
  const int* cols = ei + E;

  char* ws = (char*)d_ws;
  size_t off = 0;
  auto alloc = [&](size_t bytes) {
    void* p = ws + off;
    off = (off + bytes + 255) & ~(size_t)255;
    return p;
  };
  float* deg    = (float*)alloc(NN * 4);
  int*   counts = (int*)alloc(NN * 4);
  int*   fill   = (int*)alloc(NN * 4);
  int*   row_ptr= (int*)alloc((NN + 1) * 4);
  int*   col_s  = (int*)alloc((size_t)E * 4);
  float* w_s    = (float*)alloc((size_t)E * 4);
  float* diags  = (float*)alloc((size_t)TSTEPS * NN * 4);
  size_t fixed = off;

  // choose largest slab width that fits in remaining workspace
  int S = 64;
  for (int cand = 1024; cand >= 64; cand >>= 1) {
    size_t need = fixed + 2 * ((size_t)NN * cand * 4 + 256);
    if (need <= ws_size) { S = cand; break; }
  }
  float* bufA = (float*)alloc((size_t)NN * S * 4);
  float* bufB = (float*)alloc((size_t)NN * S * 4);

  hipMemsetAsync(deg, 0, NN * 4, stream);
  hipMemsetAsync(counts, 0, NN * 4, stream);
  hipMemsetAsync(fill, 0, NN * 4, stream);

  int eb = (E + 255) / 256;
  deg_counts_kernel<<<eb, 256, 0, stream>>>(rows, cols, ew, deg, counts, E);
  scan_kernel<<<1, 1024, 0, stream>>>(counts, row_ptr);
  csr_scatter_kernel<<<eb, 256, 0, stream>>>(rows, cols, ew, deg, row_ptr, fill,
                                             col_s, w_s, E);

  switch (S) {
    case 1024: run_slabs<1024>(rows, cols, ew, deg, row_ptr, col_s, w_s, diags, bufA, bufB, E, stream); break;
    case 512:  run_slabs<512>(rows, cols, ew, deg, row_ptr, col_s, w_s, diags, bufA, bufB, E, stream); break;
    case 256:  run_slabs<256>(rows, cols, ew, deg, row_ptr, col_s, w_s, diags, bufA, bufB, E, stream); break;
    case 128:  run_slabs<128>(rows, cols, ew, deg, row_ptr, col_s, w_s, diags, bufA, bufB, E, stream); break;
    default:   run_slabs<64>(rows, cols, ew, deg, row_ptr, col_s, w_s, diags, bufA, bufB, E, stream); break;
  }

  finalize_kernel<<<TSTEPS + 1, 256, 0, stream>>>(diags, (float*)d_out);
}

// Round 2
// 289.809 us; speedup vs baseline: 3.5619x; 3.5619x over previous
//
#include <hip/hip_runtime.h>

#define NN 4096
#define TSTEPS 8
#define EPSW 1e-12f
#define SLABW 512
#define NSLAB 8
#define LSLAB 9
#define SLAB_ELEMS ((size_t)NN * SLABW)  // 2^21

typedef unsigned int uint32;
typedef uint32 uint4v __attribute__((ext_vector_type(4)));

__device__ __forceinline__ uint32 bf16rn(float f) {
  uint32 b = __float_as_uint(f);
  return (b + 0x7FFFu + ((b >> 16) & 1u)) >> 16;
}

// ---------------------------------------------------------------------------
// Build: degree (column sums) + per-row edge counts
// ---------------------------------------------------------------------------
__global__ __launch_bounds__(256) void deg_counts_kernel(
    const int* __restrict__ rows, const int* __restrict__ cols,
    const float* __restrict__ ew, float* __restrict__ deg,
    int* __restrict__ counts, int E) {
  int e = blockIdx.x * 256 + threadIdx.x;
  if (e >= E) return;
  atomicAdd(deg + cols[e], ew[e]);
  atomicAdd(counts + rows[e], 1);
}

__global__ __launch_bounds__(1024) void scan_kernel(const int* __restrict__ counts,
                                                    int* __restrict__ row_ptr) {
  __shared__ int sm[1024];
  int tid = threadIdx.x;
  int b = tid * 4;
  int c0 = counts[b], c1 = counts[b + 1], c2 = counts[b + 2], c3 = counts[b + 3];
  sm[tid] = c0 + c1 + c2 + c3;
  __syncthreads();
  for (int off = 1; off < 1024; off <<= 1) {
    int v = (tid >= off) ? sm[tid - off] : 0;
    __syncthreads();
    sm[tid] += v;
    __syncthreads();
  }
  int excl = (tid == 0) ? 0 : sm[tid - 1];
  row_ptr[b]     = excl;
  row_ptr[b + 1] = excl + c0;
  row_ptr[b + 2] = excl + c0 + c1;
  row_ptr[b + 3] = excl + c0 + c1 + c2;
  if (tid == 1023) row_ptr[NN] = sm[1023];
}

__global__ __launch_bounds__(256) void csr_scatter_kernel(
    const int* __restrict__ rows, const int* __restrict__ cols,
    const float* __restrict__ ew, const float* __restrict__ deg,
    const int* __restrict__ row_ptr, int* __restrict__ fill,
    int* __restrict__ col_s, float* __restrict__ w_s, int E) {
  int e = blockIdx.x * 256 + threadIdx.x;
  if (e >= E) return;
  int r = rows[e], c = cols[e];
  float w = ew[e] / fmaxf(deg[c], EPSW);
  int pos = row_ptr[r] + atomicAdd(fill + r, 1);
  col_s[pos] = c;
  w_s[pos] = w;
}

// ---------------------------------------------------------------------------
// P1 scatter: pass p covers slabs [4p, 4p+4). F layout: [sl 0..3][NN][SLABW] fp32
// ---------------------------------------------------------------------------
__global__ __launch_bounds__(256) void scatter_p1_pass(
    const int* __restrict__ rows, const int* __restrict__ cols,
    const float* __restrict__ ew, const float* __restrict__ deg,
    float* __restrict__ F, int E, int p) {
  int e = blockIdx.x * 256 + threadIdx.x;
  if (e >= E) return;
  int c = cols[e];
  int sl = (c >> LSLAB) - (p << 2);
  if (sl < 0 || sl >= 4) return;
  int r = rows[e];
  float w = ew[e] / fmaxf(deg[c], EPSW);
  atomicAdd(F + ((size_t)sl * NN + r) * SLABW + (c & (SLABW - 1)), w);
}

// Convert pass-p fp32 F -> bf16 bufA (slabbed), fused diag(M^1) extraction.
__global__ __launch_bounds__(256) void convert_pass(
    const float* __restrict__ F, ushort* __restrict__ dstA,
    float* __restrict__ diags, int p) {
  size_t flat = ((size_t)blockIdx.x * 256 + threadIdx.x) * 8;
  float4 a = *(const float4*)(F + flat);
  float4 b = *(const float4*)(F + flat + 4);
  uint4v o;
  o.x = bf16rn(a.x) | (bf16rn(a.y) << 16);
  o.y = bf16rn(a.z) | (bf16rn(a.w) << 16);
  o.z = bf16rn(b.x) | (bf16rn(b.y) << 16);
  o.w = bf16rn(b.z) | (bf16rn(b.w) << 16);
  __builtin_nontemporal_store(o, (uint4v*)(dstA + (size_t)p * 4 * SLAB_ELEMS + flat));
  int sl = (int)(flat >> 21);
  int rem = (int)(flat & ((1u << 21) - 1));
  int i = rem >> LSLAB;
  int c0 = rem & (SLABW - 1);
  int gc = (((p << 2) + sl) << LSLAB) + c0;
  int j = i - gc;
  if (j >= 0 && j < 8) {
    float v;
    switch (j) {
      case 0: v = a.x; break; case 1: v = a.y; break;
      case 2: v = a.z; break; case 3: v = a.w; break;
      case 4: v = b.x; break; case 5: v = b.y; break;
      case 6: v = b.z; break; default: v = b.w; break;
    }
    diags[i] = v;
  }
}

// ---------------------------------------------------------------------------
// SpMM step, all 8 slabs concurrently. slab = bid & 7 -> rides XCD round-robin
// so each XCD's L2 holds one slab's src (4 MB). dst stored non-temporally.
// block = 64 threads (1 wave), each thread owns 8 bf16 columns.
// ---------------------------------------------------------------------------
__global__ __launch_bounds__(64) void spmm_kernel(
    const ushort* __restrict__ src, ushort* __restrict__ dst,
    const int* __restrict__ row_ptr, const int* __restrict__ col_s,
    const float* __restrict__ w_s, float* __restrict__ diags, int tIdx) {
  int bid = blockIdx.x;
  int slab = bid & (NSLAB - 1);
  int i = bid >> 3;
  int tid = threadIdx.x;
  int e0 = row_ptr[i], e1 = row_ptr[i + 1];
  __shared__ int sc[64];
  __shared__ float sw[64];
  float acc[8];
#pragma unroll
  for (int q = 0; q < 8; ++q) acc[q] = 0.f;
  const ushort* sbase = src + (size_t)slab * SLAB_ELEMS + tid * 8;

  for (int base = e0; base < e1; base += 64) {
    int cnt = min(64, e1 - base);
    if (tid < cnt) {
      sc[tid] = col_s[base + tid];
      sw[tid] = w_s[base + tid];
    }
    __syncthreads();
    int k = 0;
    for (; k + 4 <= cnt; k += 4) {
      uint4v u0 = *(const uint4v*)(sbase + ((size_t)sc[k]     << LSLAB));
      uint4v u1 = *(const uint4v*)(sbase + ((size_t)sc[k + 1] << LSLAB));
      uint4v u2 = *(const uint4v*)(sbase + ((size_t)sc[k + 2] << LSLAB));
      uint4v u3 = *(const uint4v*)(sbase + ((size_t)sc[k + 3] << LSLAB));
      float w0 = sw[k], w1 = sw[k + 1], w2 = sw[k + 2], w3 = sw[k + 3];
#pragma unroll
      for (int q = 0; q < 4; ++q) {
        acc[2 * q]     += w0 * __uint_as_float(u0[q] << 16);
        acc[2 * q + 1] += w0 * __uint_as_float(u0[q] & 0xFFFF0000u);
      }
#pragma unroll
      for (int q = 0; q < 4; ++q) {
        acc[2 * q]     += w1 * __uint_as_float(u1[q] << 16);
        acc[2 * q + 1] += w1 * __uint_as_float(u1[q] & 0xFFFF0000u);
      }
#pragma unroll
      for (int q = 0; q < 4; ++q) {
        acc[2 * q]     += w2 * __uint_as_float(u2[q] << 16);
        acc[2 * q + 1] += w2 * __uint_as_float(u2[q] & 0xFFFF0000u);
      }
#pragma unroll
      for (int q = 0; q < 4; ++q) {
        acc[2 * q]     += w3 * __uint_as_float(u3[q] << 16);
        acc[2 * q + 1] += w3 * __uint_as_float(u3[q] & 0xFFFF0000u);
      }
    }
    for (; k < cnt; ++k) {
      uint4v u = *(const uint4v*)(sbase + ((size_t)sc[k] << LSLAB));
      float w = sw[k];
#pragma unroll
      for (int q = 0; q < 4; ++q) {
        acc[2 * q]     += w * __uint_as_float(u[q] << 16);
        acc[2 * q + 1] += w * __uint_as_float(u[q] & 0xFFFF0000u);
      }
    }
    __syncthreads();
  }

  uint4v o;
#pragma unroll
  for (int q = 0; q < 4; ++q)
    o[q] = bf16rn(acc[2 * q]) | (bf16rn(acc[2 * q + 1]) << 16);
  __builtin_nontemporal_store(
      o, (uint4v*)(dst + (size_t)slab * SLAB_ELEMS + (size_t)i * SLABW + tid * 8));

  // fused diagonal: global col i lives in slab i>>9
  if ((i >> LSLAB) == slab) {
    int lc = i & (SLABW - 1);
    if ((lc >> 3) == tid) {
      int m = lc & 7;
      float v = acc[0];
      v = (m == 1) ? acc[1] : v;
      v = (m == 2) ? acc[2] : v;
      v = (m == 3) ? acc[3] : v;
      v = (m == 4) ? acc[4] : v;
      v = (m == 5) ? acc[5] : v;
      v = (m == 6) ? acc[6] : v;
      v = (m == 7) ? acc[7] : v;
      diags[tIdx * NN + i] = v;
    }
  }
}

// ---------------------------------------------------------------------------
// Finalize: X = [ones, diag_1..diag_8], standardize each column (ddof=0)
// ---------------------------------------------------------------------------
__global__ __launch_bounds__(256) void finalize_kernel(const float* __restrict__ diags,
                                                       float* __restrict__ out) {
  int k = blockIdx.x;  // 0..8
  int tid = threadIdx.x;
  float vals[16];
  float sum = 0.f, sq = 0.f;
#pragma unroll
  for (int j = 0; j < 16; ++j) {
    int i = j * 256 + tid;
    float v = (k == 0) ? 1.0f : diags[(k - 1) * NN + i];
    vals[j] = v;
    sum += v;
    sq += v * v;
  }
#pragma unroll
  for (int off = 32; off; off >>= 1) {
    sum += __shfl_down(sum, off);
    sq += __shfl_down(sq, off);
  }
  __shared__ float s0[4], s1[4];
  __shared__ float smean, sinv;
  int wid = tid >> 6, lane = tid & 63;
  if (lane == 0) { s0[wid] = sum; s1[wid] = sq; }
  __syncthreads();
  if (tid == 0) {
    float S = s0[0] + s0[1] + s0[2] + s0[3];
    float Q = s1[0] + s1[1] + s1[2] + s1[3];
    float mean = S / (float)NN;
    float var = Q / (float)NN - mean * mean;
    var = fmaxf(var, 0.f);
    float sd = fmaxf(sqrtf(var), 1e-6f);
    smean = mean;
    sinv = 1.f / sd;
  }
  __syncthreads();
#pragma unroll
  for (int j = 0; j < 16; ++j) {
    int i = j * 256 + tid;
    out[i * (TSTEPS + 1) + k] = (vals[j] - smean) * sinv;
  }
}

// ---------------------------------------------------------------------------
// Host driver
// ---------------------------------------------------------------------------
extern "C" void kernel_launch(void* const* d_in, const int* in_sizes, int n_in,
                              void* d_out, int out_size, void* d_ws, size_t ws_size,
                              hipStream_t stream) {
  const int* ei = (const int*)d_in[0];
  const float* ew = (const float*)d_in[1];
  int E = in_sizes[1];
  const int* rows = ei;
  const int* cols = ei + E;

  char* ws = (char*)d_ws;
  size_t off = 0;
  auto alloc = [&](size_t bytes) {
    void* p = ws + off;
    off = (off + bytes + 255) & ~(size_t)255;
    return p;
  };
  float* deg     = (float*)alloc(NN * 4);
  int*   counts  = (int*)alloc(NN * 4);
  int*   fill    = (int*)alloc(NN * 4);
  int*   row_ptr = (int*)alloc((NN + 1) * 4);
  int*   col_s   = (int*)alloc((size_t)E * 4);
  float* w_s     = (float*)alloc((size_t)E * 4);
  float* diags   = (float*)alloc((size_t)TSTEPS * NN * 4);
  ushort* bufA   = (ushort*)alloc((size_t)NN * NN * 2);  // 33.5 MB bf16
  void*   bufBv  = alloc((size_t)NN * NN * 2);           // 33.5 MB: F (fp32 half-pass) / bf16 pong

  hipMemsetAsync(deg, 0, NN * 4, stream);
  hipMemsetAsync(counts, 0, NN * 4, stream);
  hipMemsetAsync(fill, 0, NN * 4, stream);

  int eb = (E + 255) / 256;
  deg_counts_kernel<<<eb, 256, 0, stream>>>(rows, cols, ew, deg, counts, E);
  scan_kernel<<<1, 1024, 0, stream>>>(counts, row_ptr);
  csr_scatter_kernel<<<eb, 256, 0, stream>>>(rows, cols, ew, deg, row_ptr, fill,
                                             col_s, w_s, E);

  // P1 in two fp32 half-passes (4 slabs each) staged in bufB, converted to bf16 bufA
  float* F = (float*)bufBv;
  int cvblocks = (int)((4 * SLAB_ELEMS / 8) / 256);  // 4096
  for (int p = 0; p < 2; ++p) {
    hipMemsetAsync(F, 0, 4 * SLAB_ELEMS * sizeof(float), stream);
    scatter_p1_pass<<<eb, 256, 0, stream>>>(rows, cols, ew, deg, F, E, p);
    convert_pass<<<cvblocks, 256, 0, stream>>>(F, bufA, diags, p);
  }

  ushort* srcb = bufA;
  ushort* dstb = (ushort*)bufBv;
  for (int t = 2; t <= TSTEPS; ++t) {
    spmm_kernel<<<NN * NSLAB, 64, 0, stream>>>(srcb, dstb, row_ptr, col_s, w_s,
                                               diags, t - 1);
    ushort* tmp = srcb; srcb = dstb; dstb = tmp;
  }

  finalize_kernel<<<TSTEPS + 1, 256, 0, stream>>>(diags, (float*)d_out);
}

// Round 3
// 146.695 us; speedup vs baseline: 7.0369x; 1.9756x over previous
//
#include <hip/hip_runtime.h>

#define NN 4096
#define TSTEPS 8
#define EPSW 1e-12f
#define SLABW 512
#define NSLAB 8
#define LSLAB 9
#define SLAB_ELEMS ((size_t)NN * SLABW)  // 2^21

typedef unsigned int uint32;
typedef uint32 uint4v __attribute__((ext_vector_type(4)));

__device__ __forceinline__ uint32 bf16rn(float f) {
  uint32 b = __float_as_uint(f);
  return (b + 0x7FFFu + ((b >> 16) & 1u)) >> 16;
}
__device__ __forceinline__ float bf2f(ushort u) {
  return __uint_as_float(((uint32)u) << 16);
}

// ---------------------------------------------------------------------------
// Build: degree (column sums) + per-row edge counts
// ---------------------------------------------------------------------------
__global__ __launch_bounds__(256) void deg_counts_kernel(
    const int* __restrict__ rows, const int* __restrict__ cols,
    const float* __restrict__ ew, float* __restrict__ deg,
    int* __restrict__ counts, int E) {
  int e = blockIdx.x * 256 + threadIdx.x;
  if (e >= E) return;
  atomicAdd(deg + cols[e], ew[e]);
  atomicAdd(counts + rows[e], 1);
}

__global__ __launch_bounds__(1024) void scan_kernel(const int* __restrict__ counts,
                                                    int* __restrict__ row_ptr) {
  __shared__ int sm[1024];
  int tid = threadIdx.x;
  int b = tid * 4;
  int c0 = counts[b], c1 = counts[b + 1], c2 = counts[b + 2], c3 = counts[b + 3];
  sm[tid] = c0 + c1 + c2 + c3;
  __syncthreads();
  for (int off = 1; off < 1024; off <<= 1) {
    int v = (tid >= off) ? sm[tid - off] : 0;
    __syncthreads();
    sm[tid] += v;
    __syncthreads();
  }
  int excl = (tid == 0) ? 0 : sm[tid - 1];
  row_ptr[b]     = excl;
  row_ptr[b + 1] = excl + c0;
  row_ptr[b + 2] = excl + c0 + c1;
  row_ptr[b + 3] = excl + c0 + c1 + c2;
  if (tid == 1023) row_ptr[NN] = sm[1023];
}

// CSR scatter + fused diag1 (self-loops): diags row 0 must be pre-zeroed.
__global__ __launch_bounds__(256) void csr_scatter_kernel(
    const int* __restrict__ rows, const int* __restrict__ cols,
    const float* __restrict__ ew, const float* __restrict__ deg,
    const int* __restrict__ row_ptr, int* __restrict__ fill,
    int* __restrict__ col_s, float* __restrict__ w_s,
    float* __restrict__ diags, int E) {
  int e = blockIdx.x * 256 + threadIdx.x;
  if (e >= E) return;
  int r = rows[e], c = cols[e];
  float w = ew[e] / fmaxf(deg[c], EPSW);
  int pos = row_ptr[r] + atomicAdd(fill + r, 1);
  col_s[pos] = c;
  w_s[pos] = w;
  if (r == c) atomicAdd(diags + r, w);  // diag(M^1)
}

// ---------------------------------------------------------------------------
// M2 = M*M directly from CSR. One block (64 thr) per row i, dense fp32 row
// accumulator in LDS. Output bf16 in slabbed layout [slab][NN][SLABW].
// Fused diag2 = M2[i,i].
// ---------------------------------------------------------------------------
__global__ __launch_bounds__(64) void m2_csr_kernel(
    const int* __restrict__ row_ptr, const int* __restrict__ col_s,
    const float* __restrict__ w_s, ushort* __restrict__ dst,
    float* __restrict__ diags) {
  int i = blockIdx.x;
  int tid = threadIdx.x;
  __shared__ float acc[NN];
  __shared__ int sc[64];
  __shared__ float sw[64];
#pragma unroll
  for (int k = 0; k < NN / 64; ++k) acc[k * 64 + tid] = 0.f;
  int e0 = row_ptr[i], e1 = row_ptr[i + 1];
  __syncthreads();
  for (int base = e0; base < e1; base += 64) {
    int cnt = min(64, e1 - base);
    if (tid < cnt) {
      sc[tid] = col_s[base + tid];
      sw[tid] = w_s[base + tid];
    }
    __syncthreads();
    for (int e = 0; e < cnt; ++e) {
      int j = sc[e];
      float we = sw[e];
      int f0 = row_ptr[j], f1 = row_ptr[j + 1];
      for (int f = f0 + tid; f < f1; f += 64)
        atomicAdd(acc + col_s[f], we * w_s[f]);
    }
    __syncthreads();
  }
  if (tid == 0) diags[NN + i] = acc[i];
  // write out: col = k*64 + tid (strided -> conflict-free LDS, coalesced stores)
#pragma unroll
  for (int k = 0; k < NN / 64; ++k) {
    int c = k * 64 + tid;
    ushort h = (ushort)bf16rn(acc[c]);
    size_t idx = ((size_t)(c >> LSLAB)) * SLAB_ELEMS + (size_t)i * SLABW + (c & (SLABW - 1));
    __builtin_nontemporal_store(h, dst + idx);
  }
}

// ---------------------------------------------------------------------------
// SpMM step, all 8 slabs concurrently. slab = bid & 7 -> rides XCD round-robin.
// ---------------------------------------------------------------------------
__global__ __launch_bounds__(64) void spmm_kernel(
    const ushort* __restrict__ src, ushort* __restrict__ dst,
    const int* __restrict__ row_ptr, const int* __restrict__ col_s,
    const float* __restrict__ w_s, float* __restrict__ diags, int tIdx) {
  int bid = blockIdx.x;
  int slab = bid & (NSLAB - 1);
  int i = bid >> 3;
  int tid = threadIdx.x;
  int e0 = row_ptr[i], e1 = row_ptr[i + 1];
  __shared__ int sc[64];
  __shared__ float sw[64];
  float acc[8];
#pragma unroll
  for (int q = 0; q < 8; ++q) acc[q] = 0.f;
  const ushort* sbase = src + (size_t)slab * SLAB_ELEMS + tid * 8;

  for (int base = e0; base < e1; base += 64) {
    int cnt = min(64, e1 - base);
    if (tid < cnt) {
      sc[tid] = col_s[base + tid];
      sw[tid] = w_s[base + tid];
    }
    __syncthreads();
    int k = 0;
    for (; k + 4 <= cnt; k += 4) {
      uint4v u0 = *(const uint4v*)(sbase + ((size_t)sc[k]     << LSLAB));
      uint4v u1 = *(const uint4v*)(sbase + ((size_t)sc[k + 1] << LSLAB));
      uint4v u2 = *(const uint4v*)(sbase + ((size_t)sc[k + 2] << LSLAB));
      uint4v u3 = *(const uint4v*)(sbase + ((size_t)sc[k + 3] << LSLAB));
      float w0 = sw[k], w1 = sw[k + 1], w2 = sw[k + 2], w3 = sw[k + 3];
#pragma unroll
      for (int q = 0; q < 4; ++q) {
        acc[2 * q]     += w0 * __uint_as_float(u0[q] << 16);
        acc[2 * q + 1] += w0 * __uint_as_float(u0[q] & 0xFFFF0000u);
      }
#pragma unroll
      for (int q = 0; q < 4; ++q) {
        acc[2 * q]     += w1 * __uint_as_float(u1[q] << 16);
        acc[2 * q + 1] += w1 * __uint_as_float(u1[q] & 0xFFFF0000u);
      }
#pragma unroll
      for (int q = 0; q < 4; ++q) {
        acc[2 * q]     += w2 * __uint_as_float(u2[q] << 16);
        acc[2 * q + 1] += w2 * __uint_as_float(u2[q] & 0xFFFF0000u);
      }
#pragma unroll
      for (int q = 0; q < 4; ++q) {
        acc[2 * q]     += w3 * __uint_as_float(u3[q] << 16);
        acc[2 * q + 1] += w3 * __uint_as_float(u3[q] & 0xFFFF0000u);
      }
    }
    for (; k < cnt; ++k) {
      uint4v u = *(const uint4v*)(sbase + ((size_t)sc[k] << LSLAB));
      float w = sw[k];
#pragma unroll
      for (int q = 0; q < 4; ++q) {
        acc[2 * q]     += w * __uint_as_float(u[q] << 16);
        acc[2 * q + 1] += w * __uint_as_float(u[q] & 0xFFFF0000u);
      }
    }
    __syncthreads();
  }

  uint4v o;
#pragma unroll
  for (int q = 0; q < 4; ++q)
    o[q] = bf16rn(acc[2 * q]) | (bf16rn(acc[2 * q + 1]) << 16);
  __builtin_nontemporal_store(
      o, (uint4v*)(dst + (size_t)slab * SLAB_ELEMS + (size_t)i * SLABW + tid * 8));

  if ((i >> LSLAB) == slab) {
    int lc = i & (SLABW - 1);
    if ((lc >> 3) == tid) {
      int m = lc & 7;
      float v = acc[0];
      v = (m == 1) ? acc[1] : v;
      v = (m == 2) ? acc[2] : v;
      v = (m == 3) ? acc[3] : v;
      v = (m == 4) ? acc[4] : v;
      v = (m == 5) ? acc[5] : v;
      v = (m == 6) ? acc[6] : v;
      v = (m == 7) ? acc[7] : v;
      diags[tIdx * NN + i] = v;
    }
  }
}

// ---------------------------------------------------------------------------
// Trace products: diag5 = <M2,M3^T>, diag6 = <M3,M3^T>, diag7 = <M3,M4^T>,
// diag8 = <M4,M4^T>. diags rows 4..7 must be pre-zeroed (atomic accumulate).
// Grid: 512 blocks: bi = bid>>3 (row block of 64), jc = bid&7 (8 bj tiles).
// Matrices are in slabbed layout [slab][NN][SLABW] bf16.
// ---------------------------------------------------------------------------
__device__ __forceinline__ size_t slab_addr(int row, int col) {
  return ((size_t)(col >> LSLAB)) * SLAB_ELEMS + (size_t)row * SLABW + (col & (SLABW - 1));
}
__device__ __forceinline__ float elem8(uint4v lo, uint4v hi, int c) {
  uint32 u = (c < 8) ? lo[(c & 7) >> 1] : hi[(c & 7) >> 1];
  return __uint_as_float((c & 1) ? (u & 0xFFFF0000u) : (u << 16));
}

__global__ __launch_bounds__(256) void trace_kernel(
    const ushort* __restrict__ M2, const ushort* __restrict__ M3,
    const ushort* __restrict__ M4, float* __restrict__ diags) {
  int bid = blockIdx.x;
  int bi = bid >> 3, jc = bid & 7;
  int tid = threadIdx.x;
  __shared__ ushort b3[64 * 64], b4[64 * 64];
  __shared__ float red[4][4][64];
  // load mapping: lr = row, lc0 = col quarter
  int lr = tid >> 2, lc0 = (tid & 3) * 16;
  // compute mapping: r = local output row (whole wave spans 64 rows), jq = j quarter
  int r = tid & 63, jq = tid >> 6;
  float s5 = 0.f, s6 = 0.f, s7 = 0.f, s8 = 0.f;

  for (int it = 0; it < 8; ++it) {
    int bj = jc * 8 + it;
    {  // stage B-tiles (rows of M3/M4 at block-row bj, cols bi*64..) with XOR swizzle
      int gj = bj * 64 + lr;
      int gc = bi * 64 + lc0;
      size_t base = slab_addr(gj, gc);
      uint4v v3a = *(const uint4v*)(M3 + base);
      uint4v v3b = *(const uint4v*)(M3 + base + 8);
      uint4v v4a = *(const uint4v*)(M4 + base);
      uint4v v4b = *(const uint4v*)(M4 + base + 8);
      int cb0 = (lc0 >> 3) ^ (lr & 7);
      int cb1 = ((lc0 >> 3) + 1) ^ (lr & 7);
      *(uint4v*)(b3 + lr * 64 + cb0 * 8) = v3a;
      *(uint4v*)(b3 + lr * 64 + cb1 * 8) = v3b;
      *(uint4v*)(b4 + lr * 64 + cb0 * 8) = v4a;
      *(uint4v*)(b4 + lr * 64 + cb1 * 8) = v4b;
    }
    __syncthreads();
    // A tiles straight: row gi, cols bj*64 + jq*16 + (0..15)
    int gi = bi * 64 + r;
    int gc0 = bj * 64 + jq * 16;
    size_t abase = slab_addr(gi, gc0);
    uint4v a2a = *(const uint4v*)(M2 + abase);
    uint4v a2b = *(const uint4v*)(M2 + abase + 8);
    uint4v a3a = *(const uint4v*)(M3 + abase);
    uint4v a3b = *(const uint4v*)(M3 + abase + 8);
    uint4v a4a = *(const uint4v*)(M4 + abase);
    uint4v a4b = *(const uint4v*)(M4 + abase + 8);
#pragma unroll
    for (int c = 0; c < 16; ++c) {
      int jj = jq * 16 + c;
      int idx = jj * 64 + ((((r >> 3) ^ (jj & 7)) << 3) | (r & 7));
      float bv3 = bf2f(b3[idx]);
      float bv4 = bf2f(b4[idx]);
      float av2 = elem8(a2a, a2b, c);
      float av3 = elem8(a3a, a3b, c);
      float av4 = elem8(a4a, a4b, c);
      s5 += av2 * bv3;
      s6 += av3 * bv3;
      s7 += av3 * bv4;
      s8 += av4 * bv4;
    }
    __syncthreads();
  }
  red[0][jq][r] = s5;
  red[1][jq][r] = s6;
  red[2][jq][r] = s7;
  red[3][jq][r] = s8;
  __syncthreads();
  if (tid < 64) {
    int gi = bi * 64 + tid;
#pragma unroll
    for (int v = 0; v < 4; ++v) {
      float s = red[v][0][tid] + red[v][1][tid] + red[v][2][tid] + red[v][3][tid];
      atomicAdd(diags + (4 + v) * NN + gi, s);
    }
  }
}

// ---------------------------------------------------------------------------
// Finalize: X = [ones, diag_1..diag_8], standardize each column (ddof=0)
// ---------------------------------------------------------------------------
__global__ __launch_bounds__(256) void finalize_kernel(const float* __restrict__ diags,
                                                       float* __restrict__ out) {
  int k = blockIdx.x;  // 0..8
  int tid = threadIdx.x;
  float vals[16];
  float sum = 0.f, sq = 0.f;
#pragma unroll
  for (int j = 0; j < 16; ++j) {
    int i = j * 256 + tid;
    float v = (k == 0) ? 1.0f : diags[(k - 1) * NN + i];
    vals[j] = v;
    sum += v;
    sq += v * v;
  }
#pragma unroll
  for (int off = 32; off; off >>= 1) {
    sum += __shfl_down(sum, off);
    sq += __shfl_down(sq, off);
  }
  __shared__ float s0[4], s1[4];
  __shared__ float smean, sinv;
  int wid = tid >> 6, lane = tid & 63;
  if (lane == 0) { s0[wid] = sum; s1[wid] = sq; }
  __syncthreads();
  if (tid == 0) {
    float S = s0[0] + s0[1] + s0[2] + s0[3];
    float Q = s1[0] + s1[1] + s1[2] + s1[3];
    float mean = S / (float)NN;
    float var = Q / (float)NN - mean * mean;
    var = fmaxf(var, 0.f);
    float sd = fmaxf(sqrtf(var), 1e-6f);
    smean = mean;
    sinv = 1.f / sd;
  }
  __syncthreads();
#pragma unroll
  for (int j = 0; j < 16; ++j) {
    int i = j * 256 + tid;
    out[i * (TSTEPS + 1) + k] = (vals[j] - smean) * sinv;
  }
}

// ---------------------------------------------------------------------------
// Host driver
// ---------------------------------------------------------------------------
extern "C" void kernel_launch(void* const* d_in, const int* in_sizes, int n_in,
                              void* d_out, int out_size, void* d_ws, size_t ws_size,
                              hipStream_t stream) {
  const int* ei = (const int*)d_in[0];
  const float* ew = (const float*)d_in[1];
  int E = in_sizes[1];
  const int* rows = ei;
  const int* cols = ei + E;

  char* ws = (char*)d_ws;
  size_t off = 0;
  auto alloc = [&](size_t bytes) {
    void* p = ws + off;
    off = (off + bytes + 255) & ~(size_t)255;
    return p;
  };
  float* deg     = (float*)alloc(NN * 4);
  int*   counts  = (int*)alloc(NN * 4);
  int*   fill    = (int*)alloc(NN * 4);
  int*   row_ptr = (int*)alloc((NN + 1) * 4);
  int*   col_s   = (int*)alloc((size_t)E * 4);
  float* w_s     = (float*)alloc((size_t)E * 4);
  float* diags   = (float*)alloc((size_t)TSTEPS * NN * 4);
  ushort* bufA   = (ushort*)alloc((size_t)NN * NN * 2);  // M2
  ushort* bufB   = (ushort*)alloc((size_t)NN * NN * 2);  // M3
  ushort* bufC   = (ushort*)alloc((size_t)NN * NN * 2);  // M4

  hipMemsetAsync(deg, 0, NN * 4, stream);
  hipMemsetAsync(counts, 0, NN * 4, stream);
  hipMemsetAsync(fill, 0, NN * 4, stream);
  hipMemsetAsync(diags, 0, (size_t)TSTEPS * NN * 4, stream);

  int eb = (E + 255) / 256;
  deg_counts_kernel<<<eb, 256, 0, stream>>>(rows, cols, ew, deg, counts, E);
  scan_kernel<<<1, 1024, 0, stream>>>(counts, row_ptr);
  csr_scatter_kernel<<<eb, 256, 0, stream>>>(rows, cols, ew, deg, row_ptr, fill,
                                             col_s, w_s, diags, E);

  // M2 from CSR (+diag2)
  m2_csr_kernel<<<NN, 64, 0, stream>>>(row_ptr, col_s, w_s, bufA, diags);
  // M3 = M * M2 (+diag3), M4 = M * M3 (+diag4)
  spmm_kernel<<<NN * NSLAB, 64, 0, stream>>>(bufA, bufB, row_ptr, col_s, w_s, diags, 2);
  spmm_kernel<<<NN * NSLAB, 64, 0, stream>>>(bufB, bufC, row_ptr, col_s, w_s, diags, 3);
  // diag5..8 via trace products
  trace_kernel<<<512, 256, 0, stream>>>(bufA, bufB, bufC, diags);

  finalize_kernel<<<TSTEPS + 1, 256, 0, stream>>>(diags, (float*)d_out);
}